// Round 20
// baseline (1400.770 us; speedup 1.0000x reference)
//
#include <hip/hip_runtime.h>
#include <hip/hip_bf16.h>

#define NTOK 8192
#define HID 4096
#define NHEADS 32
#define HDIM 128
#define SEQ 1024
#define NSTEP (HID / 32)  // 128 K-steps of 32

typedef float f32x4 __attribute__((ext_vector_type(4)));
typedef short bf16x8 __attribute__((ext_vector_type(8)));

__device__ __forceinline__ ushort f2bf(float f) {
  union { float f; unsigned u; } x;
  x.f = f;
  unsigned r = x.u + 0x7fffu + ((x.u >> 16) & 1u);  // RNE
  return (ushort)(r >> 16);
}
__device__ __forceinline__ float bf2f(ushort h) {
  union { unsigned u; float f; } x;
  x.u = ((unsigned)h) << 16;
  return x.f;
}

// ---------------- bulk f32 -> bf16 convert ----------------
__global__ __launch_bounds__(256) void cvt_bf16_kernel(const float4* __restrict__ in,
                                                       ushort4* __restrict__ out, int n4) {
  int i = blockIdx.x * 256 + threadIdx.x;
  if (i < n4) {
    float4 v = in[i];
    ushort4 o;
    o.x = f2bf(v.x); o.y = f2bf(v.y); o.z = f2bf(v.z); o.w = f2bf(v.w);
    out[i] = o;
  }
}

// merged 4-weight convert: blockIdx.y selects the matrix (saves 3 launches)
__global__ __launch_bounds__(256) void cvt4_bf16_kernel(
    const float4* __restrict__ a, const float4* __restrict__ b,
    const float4* __restrict__ c, const float4* __restrict__ d,
    ushort4* __restrict__ oa, ushort4* __restrict__ ob,
    ushort4* __restrict__ oc, ushort4* __restrict__ od, int n4) {
  const int s = blockIdx.y;
  const float4* in = (s == 0) ? a : ((s == 1) ? b : ((s == 2) ? c : d));
  ushort4* out = (s == 0) ? oa : ((s == 1) ? ob : ((s == 2) ? oc : od));
  int i = blockIdx.x * 256 + threadIdx.x;
  if (i < n4) {
    float4 v = in[i];
    ushort4 o;
    o.x = f2bf(v.x); o.y = f2bf(v.y); o.z = f2bf(v.z); o.w = f2bf(v.w);
    out[i] = o;
  }
}

// ======== 256x256 GEMM  C = A * B^T, BK=32 ring-2, 2 blocks/CU ===========
// R20: R12's K-loop body (12 free-form ds_reads -> 32 MFMA, compiler
// fine-grained lgkm waits) on a DOUBLE-BUFFER (64 KB LDS -> 2 blocks/CU).
// Per step: reads -> MFMA -> lgkm0 (free) -> s_barrier (all waves' reads of
// buf[t&1] retired) -> stage tile t+2 into buf[t&1] -> vmcnt(4) (retires
// stage(t+1), counted, never 0 mid-loop) -> s_barrier. Cross-block overlap
// (m114): the co-resident block's MFMA fills this block's barrier/wait gaps.
// R8's version of this spilled ONLY because launch_bounds(512,4) capped
// VGPR at 128 < acc requirement; (512,2) keeps cap 256 (measured need ~120).

__device__ __forceinline__ void gload16(const void* g, void* l) {
  __builtin_amdgcn_global_load_lds(
      (const __attribute__((address_space(1))) unsigned int*)g,
      (__attribute__((address_space(3))) unsigned int*)l, 16, 0, 0);
}

// stage one K-step pair (A 16KB + B 16KB): 4 x gload16 per thread
__device__ __forceinline__ void stage32(const ushort* gA, const ushort* gB,
                                        int rowA0, int rowB0, int k0,
                                        ushort* ldsA, ushort* ldsB, int tid) {
  const int wid = tid >> 6, lane = tid & 63;
#pragma unroll
  for (int q = 0; q < 2; ++q) {
    int wuni = q * 8192 + wid * 1024;          // wave-uniform LDS byte base
    int off = wuni + lane * 16;                // lane's physical dest byte
    int row = off >> 6;                        // 64B rows (XOR preserves row)
    int kb = (off ^ (((row >> 1) & 3) << 4)) & 63;  // logical byte in row
    gload16(gA + (size_t)(rowA0 + row) * HID + k0 + (kb >> 1), (char*)ldsA + wuni);
    gload16(gB + (size_t)(rowB0 + row) * HID + k0 + (kb >> 1), (char*)ldsB + wuni);
  }
}

// One pipeline step. VMC: 4 = counted wait, 0 = drain, -1 = tail (no sync).
#define GSTEP(T, DO_STAGE, VMC)                                                \
  do {                                                                         \
    const char* cA = (const char*)bufA[(T) & 1];                               \
    const char* cB = (const char*)bufB[(T) & 1];                               \
    _Pragma("unroll") for (int ii = 0; ii < 8; ++ii) {                         \
      int L = (wm * 128 + ii * 16 + l15) * 64 + l4 * 16;                       \
      af[ii] = *(const bf16x8*)(cA + (L ^ swzr));                              \
    }                                                                          \
    _Pragma("unroll") for (int jj = 0; jj < 4; ++jj) {                         \
      int L = (colbase + (jj & 1) * 16 + (jj >> 1) * 64 + l15) * 64 + l4 * 16; \
      bfr[jj] = *(const bf16x8*)(cB + (L ^ swzr));                             \
    }                                                                          \
    _Pragma("unroll") for (int ii = 0; ii < 8; ++ii)                           \
        _Pragma("unroll") for (int jj = 0; jj < 4; ++jj)                       \
            acc[ii][jj] = __builtin_amdgcn_mfma_f32_16x16x32_bf16(             \
                af[ii], bfr[jj], acc[ii][jj], 0, 0, 0);                        \
    if ((VMC) >= 0) {                                                          \
      asm volatile("s_waitcnt lgkmcnt(0)" ::: "memory");                       \
      __builtin_amdgcn_s_barrier(); /* reads of buf[T&1] retired block-wide */ \
      if (DO_STAGE)                                                            \
        stage32(Abf, Bp, m0, n0, ((T) + 2) * 32, bufA[(T) & 1],                \
                bufB[(T) & 1], tid);                                           \
      if ((VMC) == 4) asm volatile("s_waitcnt vmcnt(4)" ::: "memory");         \
      else asm volatile("s_waitcnt vmcnt(0)" ::: "memory");                    \
      __builtin_amdgcn_s_barrier();                                            \
    }                                                                          \
  } while (0)

template <bool OUTF32, bool DOROPE>
__global__ __launch_bounds__(512, 2) void gemm256_kernel(
    const ushort* __restrict__ Abf,
    const ushort* __restrict__ B0, const ushort* __restrict__ B1,
    const ushort* __restrict__ B2,
    void* __restrict__ O0, void* __restrict__ O1, void* __restrict__ O2,
    int NTALL, const int* __restrict__ pos,
    const float* __restrict__ cosT, const float* __restrict__ sinT) {
  __shared__ __align__(16) ushort bufA[2][8192];  // 2 x 16 KB
  __shared__ __align__(16) ushort bufB[2][8192];  // 2 x 16 KB

  const int tid = threadIdx.x;
  const int l = tid & 63, wid = tid >> 6;
  const int wm = wid >> 2, wn = wid & 3;
  const int l15 = l & 15, l4 = l >> 4;
  const int swzr = ((l15 >> 1) & 3) << 4;
  const int colbase = (wn >> 1) * 128 + (wn & 1) * 32;  // wave col base in tile

  // XCD-aware bijective swizzle + 8-row band supertiling (nwg % 8 == 0)
  const int nwg = gridDim.x;
  const int cpx = nwg >> 3;
  const int bid = blockIdx.x;
  const int lgid = (bid & 7) * cpx + (bid >> 3);
  const int bandw = NTALL << 3;
  const int band = lgid / bandw, rem = lgid % bandw;
  const int nt = rem >> 3;
  const int mt = (band << 3) + (rem & 7);
  const int m0 = mt * 256;
  const int sel = nt >> 4;
  const int n0 = (nt & 15) * 256;
  const ushort* Bp = (sel == 0) ? B0 : ((sel == 1) ? B1 : B2);
  void* Op = (sel == 0) ? O0 : ((sel == 1) ? O1 : O2);

  f32x4 acc[8][4];
  const f32x4 zero = {0.f, 0.f, 0.f, 0.f};
#pragma unroll
  for (int i = 0; i < 8; ++i)
#pragma unroll
    for (int j = 0; j < 4; ++j) acc[i][j] = zero;

  // prologue: stage tiles 0,1; vmcnt(4) retires stage0 (stage1 in flight)
  stage32(Abf, Bp, m0, n0, 0, bufA[0], bufB[0], tid);
  stage32(Abf, Bp, m0, n0, 32, bufA[1], bufB[1], tid);
  asm volatile("s_waitcnt vmcnt(4)" ::: "memory");
  __builtin_amdgcn_s_barrier();

  bf16x8 af[8], bfr[4];
  // steady: t=0..123 stage tiles 2..125
  for (int tt = 0; tt < NSTEP - 4; tt += 4) {
    GSTEP(tt + 0, true, 4);
    GSTEP(tt + 1, true, 4);
    GSTEP(tt + 2, true, 4);
    GSTEP(tt + 3, true, 4);
  }
  GSTEP(NSTEP - 4, true, 4);   // t=124: stages 126; vmcnt(4) retires stage(125)
  GSTEP(NSTEP - 3, true, 4);   // t=125: stages 127; vmcnt(4) retires stage(126)
  GSTEP(NSTEP - 2, false, 0);  // t=126: drain stage(127)
  GSTEP(NSTEP - 1, false, -1); // t=127: no more syncs
#pragma unroll
  for (int ii = 0; ii < 8; ++ii)
#pragma unroll
    for (int jj = 0; jj < 4; ++jj)
      ;  // (acc already accumulated in GSTEP(NSTEP-1))

  if (DOROPE && sel < 2) {
    // fused RoPE: acc[i][jj] = d-part, acc[i][jj+2] = (d+64)-part, same thread
    const float qsc = (sel == 0) ? 0.08838834764831845f : 1.0f;
#pragma unroll
    for (int i = 0; i < 8; ++i) {
#pragma unroll
      for (int r = 0; r < 4; ++r) {
        const int row = m0 + wm * 128 + i * 16 + l4 * 4 + r;
        const int p = pos[row];
#pragma unroll
        for (int jj = 0; jj < 2; ++jj) {
          const int d = (wn & 1) * 32 + jj * 16 + l15;  // 0..63
          const float c = cosT[p * HDIM + d];
          const float s = sinT[p * HDIM + d];
          const float lo = acc[i][jj][r], hi = acc[i][jj + 2][r];
          const int col = n0 + colbase + jj * 16 + l15;
          ((ushort*)Op)[(size_t)row * HID + col] = f2bf((lo * c - hi * s) * qsc);
          ((ushort*)Op)[(size_t)row * HID + col + 64] = f2bf((hi * c + lo * s) * qsc);
        }
      }
    }
  } else {
#pragma unroll
    for (int i = 0; i < 8; ++i) {
      const int row = m0 + wm * 128 + i * 16 + l4 * 4;
#pragma unroll
      for (int j = 0; j < 4; ++j) {
        const int col = n0 + colbase + (j & 1) * 16 + (j >> 1) * 64 + l15;
#pragma unroll
        for (int r = 0; r < 4; ++r) {
          float v = acc[i][j][r];
          if constexpr (OUTF32)
            ((float*)Op)[(size_t)(row + r) * HID + col] = v;
          else
            ((ushort*)Op)[(size_t)(row + r) * HID + col] = f2bf(v);
        }
      }
    }
  }
}

// ================= OLD 128x128 GEMM (fallback path only) =================
template <bool ISBF>
__device__ __forceinline__ void stage_tile(ushort* lds, const void* gp, int row0, int k0, int tid) {
  if constexpr (ISBF) {
    const ushort* g = (const ushort*)gp;
#pragma unroll
    for (int i = 0; i < 2; ++i) {
      int row = (tid >> 2) + i * 64;
      int gr = tid & 3;
      bf16x8 v = *(const bf16x8*)(g + (size_t)(row0 + row) * HID + k0 + gr * 8);
      int gs = gr ^ ((row >> 1) & 3);
      *(bf16x8*)((char*)lds + row * 64 + gs * 16) = v;
    }
  } else {
    const float* g = (const float*)gp;
    int row = tid >> 1;
    const float* rp = g + (size_t)(row0 + row) * HID + k0;
#pragma unroll
    for (int i = 0; i < 2; ++i) {
      int gr = (tid & 1) * 2 + i;
      float4 a = *(const float4*)(rp + gr * 8);
      float4 b = *(const float4*)(rp + gr * 8 + 4);
      bf16x8 v;
      v[0] = (short)f2bf(a.x); v[1] = (short)f2bf(a.y);
      v[2] = (short)f2bf(a.z); v[3] = (short)f2bf(a.w);
      v[4] = (short)f2bf(b.x); v[5] = (short)f2bf(b.y);
      v[6] = (short)f2bf(b.z); v[7] = (short)f2bf(b.w);
      int gs = gr ^ ((row >> 1) & 3);
      *(bf16x8*)((char*)lds + row * 64 + gs * 16) = v;
    }
  }
}

template <bool ABF, bool BBF, bool OUTF32>
__global__ __launch_bounds__(256) void gemm_bt_kernel(
    const void* __restrict__ Ap,
    const void* __restrict__ B0, const void* __restrict__ B1, const void* __restrict__ B2,
    void* __restrict__ O0, void* __restrict__ O1, void* __restrict__ O2,
    int ntiles_per_w) {
  __shared__ __align__(16) ushort lA[128 * 32];
  __shared__ __align__(16) ushort lB[128 * 32];
  const int tid = threadIdx.x;
  const int l = tid & 63, wid = tid >> 6;
  const int wm = wid >> 1, wn = wid & 1;
  const int l15 = l & 15, l4 = l >> 4;
  const int mt0 = blockIdx.y * 128;
  const int ntile = blockIdx.x;
  const int sel = ntile / ntiles_per_w;
  const int nt0 = (ntile % ntiles_per_w) * 128;
  const void* Bp = (sel == 0) ? B0 : ((sel == 1) ? B1 : B2);
  void* Op = (sel == 0) ? O0 : ((sel == 1) ? O1 : O2);

  const f32x4 zero = {0.f, 0.f, 0.f, 0.f};
  f32x4 acc[4][4];
#pragma unroll
  for (int i = 0; i < 4; ++i)
#pragma unroll
    for (int j = 0; j < 4; ++j) acc[i][j] = zero;

  for (int k0 = 0; k0 < HID; k0 += 32) {
    stage_tile<ABF>(lA, Ap, mt0, k0, tid);
    stage_tile<BBF>(lB, Bp, nt0, k0, tid);
    __syncthreads();
    bf16x8 af[4], bfr[4];
#pragma unroll
    for (int i = 0; i < 4; ++i) {
      int rowa = wm * 64 + i * 16 + l15;
      int ga = l4 ^ ((rowa >> 1) & 3);
      af[i] = *(const bf16x8*)((const char*)lA + rowa * 64 + ga * 16);
      int rowb = wn * 64 + i * 16 + l15;
      int gb = l4 ^ ((rowb >> 1) & 3);
      bfr[i] = *(const bf16x8*)((const char*)lB + rowb * 64 + gb * 16);
    }
#pragma unroll
    for (int i = 0; i < 4; ++i)
#pragma unroll
      for (int j = 0; j < 4; ++j)
        acc[i][j] = __builtin_amdgcn_mfma_f32_16x16x32_bf16(af[i], bfr[j], acc[i][j], 0, 0, 0);
    __syncthreads();
  }

#pragma unroll
  for (int i = 0; i < 4; ++i) {
#pragma unroll
    for (int j = 0; j < 4; ++j) {
      int row = mt0 + wm * 64 + i * 16 + l4 * 4;
      int col = nt0 + wn * 64 + j * 16 + l15;
#pragma unroll
      for (int r = 0; r < 4; ++r) {
        float v = acc[i][j][r];
        if constexpr (OUTF32)
          ((float*)Op)[(size_t)(row + r) * HID + col] = v;
        else
          ((ushort*)Op)[(size_t)(row + r) * HID + col] = f2bf(v);
      }
    }
  }
}

// ---------------- RoPE (fallback path only) ----------------
__global__ __launch_bounds__(256) void rope_kernel(
    ushort* __restrict__ q, ushort* __restrict__ k,
    const float* __restrict__ cosT, const float* __restrict__ sinT,
    const int* __restrict__ pos) {
  int idx = blockIdx.x * 256 + threadIdx.x;
  int token = idx >> 8;
  int head = (idx >> 3) & 31;
  int c = idx & 7;
  int p = pos[token];
  size_t base = (size_t)token * HID + head * HDIM + c * 8;
  bf16x8 ql = *(bf16x8*)(q + base);
  bf16x8 qh = *(bf16x8*)(q + base + 64);
  bf16x8 kl = *(bf16x8*)(k + base);
  bf16x8 kh = *(bf16x8*)(k + base + 64);
  float4 c0 = *(const float4*)(cosT + (size_t)p * HDIM + c * 8);
  float4 c1 = *(const float4*)(cosT + (size_t)p * HDIM + c * 8 + 4);
  float4 s0 = *(const float4*)(sinT + (size_t)p * HDIM + c * 8);
  float4 s1 = *(const float4*)(sinT + (size_t)p * HDIM + c * 8 + 4);
  float cs[8] = {c0.x, c0.y, c0.z, c0.w, c1.x, c1.y, c1.z, c1.w};
  float sn[8] = {s0.x, s0.y, s0.z, s0.w, s1.x, s1.y, s1.z, s1.w};
  const float qsc = 0.08838834764831845f;  // 1/sqrt(128)
  bf16x8 qlo, qho, klo, kho;
#pragma unroll
  for (int j = 0; j < 8; ++j) {
    float qlf = bf2f((ushort)ql[j]), qhf = bf2f((ushort)qh[j]);
    float klf = bf2f((ushort)kl[j]), khf = bf2f((ushort)kh[j]);
    qlo[j] = (short)f2bf((qlf * cs[j] - qhf * sn[j]) * qsc);
    qho[j] = (short)f2bf((qhf * cs[j] + qlf * sn[j]) * qsc);
    klo[j] = (short)f2bf(klf * cs[j] - khf * sn[j]);
    kho[j] = (short)f2bf(khf * cs[j] + klf * sn[j]);
  }
  *(bf16x8*)(q + base) = qlo;
  *(bf16x8*)(q + base + 64) = qho;
  *(bf16x8*)(k + base) = klo;
  *(bf16x8*)(k + base + 64) = kho;
}

// ---------------- causal flash attention (R19 exact -- best measured) ------
// grid (qblk=8, head=32, batch=8), 512 thr = 8 waves x 16 q-rows (QBLK=128).
// T14 async reg staging + LPT + frozen-max + deferred per-lane lrow.
__global__ __launch_bounds__(512) void attn_kernel(
    const ushort* __restrict__ qb, const ushort* __restrict__ kb,
    const ushort* __restrict__ vb, ushort* __restrict__ ob) {
  __shared__ __align__(16) ushort lK[32 * 128];   // [key][d], rows 256B, swz g^=(r&7)
  __shared__ __align__(16) ushort lVT[128 * 32];  // [d][key], rows 64B, swz g^=((d>>1)&3)
  __shared__ __align__(16) ushort lP[8][16 * 32]; // per-wave P [q][key]

  const int tid = threadIdx.x;
  const int l = tid & 63, wid = tid >> 6;
  const int l15 = l & 15, l4 = l >> 4;
  const int q0 = (gridDim.x - 1 - blockIdx.x) * 128;  // LPT: heavy first
  const int h = blockIdx.y;
  const size_t seqbase = (size_t)blockIdx.z * SEQ;

  const int sr = tid >> 4, sg = tid & 15;         // K: row sr, granule sg
  const int vd = tid & 127, vj0 = (tid >> 7) * 8; // V: col vd, keys vj0..vj0+7
  const ushort* kgp = kb + (seqbase + sr) * HID + h * HDIM + sg * 8;
  const ushort* vgp = vb + (seqbase + vj0) * HID + h * HDIM + vd;

  bf16x8 qf[4];
  {
    const ushort* qp = qb + (seqbase + q0 + wid * 16 + l15) * HID + h * HDIM + l4 * 8;
#pragma unroll
    for (int kk = 0; kk < 4; ++kk) qf[kk] = *(const bf16x8*)(qp + kk * 32);
  }

  const f32x4 zero = {0.f, 0.f, 0.f, 0.f};
  f32x4 oacc[8];
#pragma unroll
  for (int t = 0; t < 8; ++t) oacc[t] = zero;
  float mrow[4];
  float lrow[4] = {0.f, 0.f, 0.f, 0.f};  // per-lane partial sums

  const int ntile = q0 / 32 + 4;
  const int qrow = q0 + wid * 16 + l4 * 4;

  bf16x8 kreg = *(const bf16x8*)(kgp);
  bf16x8 vreg;
#pragma unroll
  for (int j = 0; j < 8; ++j) vreg[j] = (short)vgp[(size_t)j * HID];

  for (int kt = 0; kt < ntile; ++kt) {
    const int k0 = kt * 32;
    __builtin_amdgcn_s_barrier();
    {
      int gs = sg ^ (sr & 7);
      *(bf16x8*)((char*)lK + sr * 256 + gs * 16) = kreg;
    }
    {
      int g = tid >> 7;
      int gs = g ^ ((vd >> 1) & 3);
      *(bf16x8*)((char*)lVT + vd * 64 + gs * 16) = vreg;
    }
    if (kt + 1 < ntile) {
      const size_t off = (size_t)(k0 + 32) * HID;
      kreg = *(const bf16x8*)(kgp + off);
#pragma unroll
      for (int j = 0; j < 8; ++j) vreg[j] = (short)vgp[off + (size_t)j * HID];
    }
    __syncthreads();

    f32x4 s[2];
#pragma unroll
    for (int hf = 0; hf < 2; ++hf) {
      f32x4 c = zero;
      int row = hf * 16 + l15;
#pragma unroll
      for (int kk = 0; kk < 4; ++kk) {
        int gs = (kk * 4 + l4) ^ (row & 7);
        bf16x8 kf = *(const bf16x8*)((const char*)lK + row * 256 + gs * 16);
        c = __builtin_amdgcn_mfma_f32_16x16x32_bf16(qf[kk], kf, c, 0, 0, 0);
      }
      s[hf] = c;
    }

    if (kt == 0) {
#pragma unroll
      for (int r = 0; r < 4; ++r) {
        float s0 = (k0 + l15 <= qrow + r) ? s[0][r] : -1e30f;
        float s1 = (k0 + 16 + l15 <= qrow + r) ? s[1][r] : -1e30f;
        float tmax = fmaxf(s0, s1);
#pragma unroll
        for (int off = 8; off; off >>= 1) tmax = fmaxf(tmax, __shfl_xor(tmax, off));
        mrow[r] = tmax;
        float p0 = __expf(s0 - tmax);
        float p1 = __expf(s1 - tmax);
        lrow[r] = p0 + p1;  // per-lane partial
        lP[wid][(l4 * 4 + r) * 32 + l15] = f2bf(p0);
        lP[wid][(l4 * 4 + r) * 32 + 16 + l15] = f2bf(p1);
      }
    } else {
#pragma unroll
      for (int r = 0; r < 4; ++r) {
        float s0 = (k0 + l15 <= qrow + r) ? s[0][r] : -1e30f;
        float s1 = (k0 + 16 + l15 <= qrow + r) ? s[1][r] : -1e30f;
        float p0 = __expf(s0 - mrow[r]);
        float p1 = __expf(s1 - mrow[r]);
        lrow[r] += p0 + p1;
        lP[wid][(l4 * 4 + r) * 32 + l15] = f2bf(p0);
        lP[wid][(l4 * 4 + r) * 32 + 16 + l15] = f2bf(p1);
      }
    }
    asm volatile("s_waitcnt lgkmcnt(0)" ::: "memory");
    __builtin_amdgcn_sched_barrier(0);

    bf16x8 pf = *(const bf16x8*)((const char*)&lP[wid][0] + l15 * 64 + l4 * 16);
#pragma unroll
    for (int t = 0; t < 8; ++t) {
      int d = t * 16 + l15;
      int gs = l4 ^ ((d >> 1) & 3);
      bf16x8 vf = *(const bf16x8*)((const char*)lVT + d * 64 + gs * 16);
      oacc[t] = __builtin_amdgcn_mfma_f32_16x16x32_bf16(pf, vf, oacc[t], 0, 0, 0);
    }
  }

  // epilogue: single 16-lane reduction of the deferred denominator
#pragma unroll
  for (int r = 0; r < 4; ++r) {
#pragma unroll
    for (int off = 8; off; off >>= 1) lrow[r] += __shfl_xor(lrow[r], off);
    float inv = 1.0f / lrow[r];
    ushort* op = ob + (seqbase + q0 + wid * 16 + l4 * 4 + r) * HID + h * HDIM + l15;
#pragma unroll
    for (int t = 0; t < 8; ++t) op[t * 16] = f2bf(oacc[t][r] * inv);
  }
}

// ---------------- driver ----------------
extern "C" void kernel_launch(void* const* d_in, const int* in_sizes, int n_in,
                              void* d_out, int out_size, void* d_ws, size_t ws_size,
                              hipStream_t stream) {
  const float* cosT = (const float*)d_in[0];
  const float* sinT = (const float*)d_in[1];
  const float* X    = (const float*)d_in[2];
  const int*   pos  = (const int*)d_in[3];
  const float* Wq = (const float*)d_in[6];
  const float* Wk = (const float*)d_in[7];
  const float* Wv = (const float*)d_in[8];
  const float* Wo = (const float*)d_in[9];
  float* out = (float*)d_out;

  char* ws = (char*)d_ws;
  const size_t QKVB = (size_t)NTOK * HID * 2;  // 64 MiB
  const size_t WB = (size_t)HID * HID * 2;     // 32 MiB
  const size_t XB = QKVB;
  ushort* qbuf = (ushort*)(ws);
  ushort* kbuf = (ushort*)(ws + QKVB);
  ushort* vbuf = (ushort*)(ws + 2 * QKVB);

  dim3 blk(256);
  const int n4x = NTOK * HID / 4;
  const int n4w = HID * HID / 4;

  const bool fast = ws_size >= 3 * QKVB + XB + 4 * WB;          // 384 MiB
  const bool mid = !fast && ws_size >= 3 * QKVB + 2 * WB &&
                   (size_t)out_size * 4 >= XB + 2 * WB;          // 256 MiB + d_out scratch

  if (fast || mid) {
    ushort *xb, *wqb, *wkb, *wvb, *wob;
    if (fast) {
      xb  = (ushort*)(ws + 3 * QKVB);
      wqb = (ushort*)(ws + 3 * QKVB + XB);
      wkb = (ushort*)(ws + 3 * QKVB + XB + WB);
      wvb = (ushort*)(ws + 3 * QKVB + XB + 2 * WB);
      wob = (ushort*)(ws + 3 * QKVB + XB + 3 * WB);
    } else {
      // stash X/Wq/Wk bf16 in d_out (fully overwritten by final GEMM)
      xb  = (ushort*)d_out;
      wqb = (ushort*)((char*)d_out + XB);
      wkb = (ushort*)((char*)d_out + XB + WB);
      wvb = (ushort*)(ws + 3 * QKVB);
      wob = (ushort*)(ws + 3 * QKVB + WB);
    }
    cvt_bf16_kernel<<<n4x / 256, blk, 0, stream>>>((const float4*)X, (ushort4*)xb, n4x);
    cvt4_bf16_kernel<<<dim3(n4w / 256, 4), blk, 0, stream>>>(
        (const float4*)Wq, (const float4*)Wk, (const float4*)Wv, (const float4*)Wo,
        (ushort4*)wqb, (ushort4*)wkb, (ushort4*)wvb, (ushort4*)wob, n4w);
    gemm256_kernel<false, true><<<dim3(32 * 48), dim3(512), 0, stream>>>(
        xb, wqb, wkb, wvb, qbuf, kbuf, vbuf, 48, pos, cosT, sinT);
    attn_kernel<<<dim3(8, 32, 8), dim3(512), 0, stream>>>(qbuf, kbuf, vbuf, qbuf);
    gemm256_kernel<true, false><<<dim3(32 * 16), dim3(512), 0, stream>>>(
        qbuf, wob, wob, wob, out, out, out, 16, pos, cosT, sinT);
  } else {
    gemm_bt_kernel<false, false, false><<<dim3(96, 64), blk, 0, stream>>>(
        X, Wq, Wk, Wv, qbuf, kbuf, vbuf, 32);
    rope_kernel<<<NTOK * NHEADS * 8 / 256, blk, 0, stream>>>(qbuf, kbuf, cosT, sinT, pos);
    attn_kernel<<<dim3(8, 32, 8), dim3(512), 0, stream>>>(qbuf, kbuf, vbuf, qbuf);
    gemm_bt_kernel<true, false, true><<<dim3(32, 64), blk, 0, stream>>>(
        qbuf, Wo, Wo, Wo, out, out, out, 32);
  }
}

// Round 21
// 1308.556 us; speedup vs baseline: 1.0705x; 1.0705x over previous
//
#include <hip/hip_runtime.h>
#include <hip/hip_bf16.h>

#define NTOK 8192
#define HID 4096
#define NHEADS 32
#define HDIM 128
#define SEQ 1024
#define NSTEP (HID / 32)  // 128 K-steps of 32

typedef float f32x4 __attribute__((ext_vector_type(4)));
typedef short bf16x8 __attribute__((ext_vector_type(8)));

__device__ __forceinline__ ushort f2bf(float f) {
  union { float f; unsigned u; } x;
  x.f = f;
  unsigned r = x.u + 0x7fffu + ((x.u >> 16) & 1u);  // RNE
  return (ushort)(r >> 16);
}
__device__ __forceinline__ float bf2f(ushort h) {
  union { unsigned u; float f; } x;
  x.u = ((unsigned)h) << 16;
  return x.f;
}

// ---------------- bulk f32 -> bf16 convert ----------------
__global__ __launch_bounds__(256) void cvt_bf16_kernel(const float4* __restrict__ in,
                                                       ushort4* __restrict__ out, int n4) {
  int i = blockIdx.x * 256 + threadIdx.x;
  if (i < n4) {
    float4 v = in[i];
    ushort4 o;
    o.x = f2bf(v.x); o.y = f2bf(v.y); o.z = f2bf(v.z); o.w = f2bf(v.w);
    out[i] = o;
  }
}

// merged 4-weight convert: blockIdx.y selects the matrix (saves 3 launches)
__global__ __launch_bounds__(256) void cvt4_bf16_kernel(
    const float4* __restrict__ a, const float4* __restrict__ b,
    const float4* __restrict__ c, const float4* __restrict__ d,
    ushort4* __restrict__ oa, ushort4* __restrict__ ob,
    ushort4* __restrict__ oc, ushort4* __restrict__ od, int n4) {
  const int s = blockIdx.y;
  const float4* in = (s == 0) ? a : ((s == 1) ? b : ((s == 2) ? c : d));
  ushort4* out = (s == 0) ? oa : ((s == 1) ? ob : ((s == 2) ? oc : od));
  int i = blockIdx.x * 256 + threadIdx.x;
  if (i < n4) {
    float4 v = in[i];
    ushort4 o;
    o.x = f2bf(v.x); o.y = f2bf(v.y); o.z = f2bf(v.z); o.w = f2bf(v.w);
    out[i] = o;
  }
}

// ================= 256x256 GEMM  C = A * B^T, BK=32 ring-4 ================
// R12 K-loop (best: MfmaUtil 51%) + R14 fused-RoPE epilogue. FROZEN.
// (R20's ring-2/2-blocks variant regressed: no co-residency materialized and
// the mid-step barrier serialized the pipeline. Ring-4 + 1 barrier/step wins.)

__device__ __forceinline__ void gload16(const void* g, void* l) {
  __builtin_amdgcn_global_load_lds(
      (const __attribute__((address_space(1))) unsigned int*)g,
      (__attribute__((address_space(3))) unsigned int*)l, 16, 0, 0);
}

// stage one K-step pair (A 16KB + B 16KB): 4 x gload16 per thread
__device__ __forceinline__ void stage32(const ushort* gA, const ushort* gB,
                                        int rowA0, int rowB0, int k0,
                                        ushort* ldsA, ushort* ldsB, int tid) {
  const int wid = tid >> 6, lane = tid & 63;
#pragma unroll
  for (int q = 0; q < 2; ++q) {
    int wuni = q * 8192 + wid * 1024;          // wave-uniform LDS byte base
    int off = wuni + lane * 16;                // lane's physical dest byte
    int row = off >> 6;                        // 64B rows (XOR preserves row)
    int kb = (off ^ (((row >> 1) & 3) << 4)) & 63;  // logical byte in row
    gload16(gA + (size_t)(rowA0 + row) * HID + k0 + (kb >> 1), (char*)ldsA + wuni);
    gload16(gB + (size_t)(rowB0 + row) * HID + k0 + (kb >> 1), (char*)ldsB + wuni);
  }
}

// One pipeline step. VMC: 4 = counted wait, 0 = drain, -1 = tail (no sync).
#define GSTEP(T, DO_STAGE, VMC)                                                \
  do {                                                                         \
    const char* cA = (const char*)ringA[(T) & 3];                              \
    const char* cB = (const char*)ringB[(T) & 3];                              \
    _Pragma("unroll") for (int ii = 0; ii < 8; ++ii) {                         \
      int L = (wm * 128 + ii * 16 + l15) * 64 + l4 * 16;                       \
      af[ii] = *(const bf16x8*)(cA + (L ^ swzr));                              \
    }                                                                          \
    _Pragma("unroll") for (int jj = 0; jj < 4; ++jj) {                         \
      int L = (colbase + (jj & 1) * 16 + (jj >> 1) * 64 + l15) * 64 + l4 * 16; \
      bfr[jj] = *(const bf16x8*)(cB + (L ^ swzr));                             \
    }                                                                          \
    if (DO_STAGE)                                                              \
      stage32(Abf, Bp, m0, n0, ((T) + 3) * 32, ringA[((T) + 3) & 3],           \
              ringB[((T) + 3) & 3], tid);                                      \
    _Pragma("unroll") for (int ii = 0; ii < 8; ++ii)                           \
        _Pragma("unroll") for (int jj = 0; jj < 4; ++jj)                       \
            acc[ii][jj] = __builtin_amdgcn_mfma_f32_16x16x32_bf16(             \
                af[ii], bfr[jj], acc[ii][jj], 0, 0, 0);                        \
    if ((VMC) >= 0) {                                                          \
      asm volatile("s_waitcnt lgkmcnt(0)" ::: "memory");                       \
      if ((VMC) == 4) asm volatile("s_waitcnt vmcnt(4)" ::: "memory");         \
      else asm volatile("s_waitcnt vmcnt(0)" ::: "memory");                    \
      __builtin_amdgcn_s_barrier();                                            \
    }                                                                          \
  } while (0)

template <bool OUTF32, bool DOROPE>
__global__ __launch_bounds__(512, 2) void gemm256_kernel(
    const ushort* __restrict__ Abf,
    const ushort* __restrict__ B0, const ushort* __restrict__ B1,
    const ushort* __restrict__ B2,
    void* __restrict__ O0, void* __restrict__ O1, void* __restrict__ O2,
    int NTALL, const int* __restrict__ pos,
    const float* __restrict__ cosT, const float* __restrict__ sinT) {
  __shared__ __align__(16) ushort ringA[4][8192];
  __shared__ __align__(16) ushort ringB[4][8192];

  const int tid = threadIdx.x;
  const int l = tid & 63, wid = tid >> 6;
  const int wm = wid >> 2, wn = wid & 3;
  const int l15 = l & 15, l4 = l >> 4;
  const int swzr = ((l15 >> 1) & 3) << 4;
  const int colbase = (wn >> 1) * 128 + (wn & 1) * 32;  // wave col base in tile

  // XCD-aware bijective swizzle + 8-row band supertiling (nwg % 8 == 0)
  const int nwg = gridDim.x;
  const int cpx = nwg >> 3;
  const int bid = blockIdx.x;
  const int lgid = (bid & 7) * cpx + (bid >> 3);
  const int bandw = NTALL << 3;
  const int band = lgid / bandw, rem = lgid % bandw;
  const int nt = rem >> 3;
  const int mt = (band << 3) + (rem & 7);
  const int m0 = mt * 256;
  const int sel = nt >> 4;
  const int n0 = (nt & 15) * 256;
  const ushort* Bp = (sel == 0) ? B0 : ((sel == 1) ? B1 : B2);
  void* Op = (sel == 0) ? O0 : ((sel == 1) ? O1 : O2);

  f32x4 acc[8][4];
  const f32x4 zero = {0.f, 0.f, 0.f, 0.f};
#pragma unroll
  for (int i = 0; i < 8; ++i)
#pragma unroll
    for (int j = 0; j < 4; ++j) acc[i][j] = zero;

  // prologue: stage steps 0,1,2; vmcnt(4) retires 0,1 (stage2 stays in flight)
  stage32(Abf, Bp, m0, n0, 0, ringA[0], ringB[0], tid);
  stage32(Abf, Bp, m0, n0, 32, ringA[1], ringB[1], tid);
  stage32(Abf, Bp, m0, n0, 64, ringA[2], ringB[2], tid);
  asm volatile("s_waitcnt vmcnt(4)" ::: "memory");
  __builtin_amdgcn_s_barrier();

  bf16x8 af[8], bfr[4];
  for (int tt = 0; tt < NSTEP - 4; tt += 4) {
    GSTEP(tt + 0, true, 4);
    GSTEP(tt + 1, true, 4);
    GSTEP(tt + 2, true, 4);
    GSTEP(tt + 3, true, 4);
  }
  GSTEP(NSTEP - 4, true, 4);   // t=124: stages slot 127; retires stage(126)
  GSTEP(NSTEP - 3, false, 0);  // t=125: drain stage(127)
  GSTEP(NSTEP - 2, false, -1); // t=126: no more syncs needed
  GSTEP(NSTEP - 1, false, -1); // t=127

  if (DOROPE && sel < 2) {
    // fused RoPE: acc[i][jj] = d-part, acc[i][jj+2] = (d+64)-part, same thread
    const float qsc = (sel == 0) ? 0.08838834764831845f : 1.0f;
#pragma unroll
    for (int i = 0; i < 8; ++i) {
#pragma unroll
      for (int r = 0; r < 4; ++r) {
        const int row = m0 + wm * 128 + i * 16 + l4 * 4 + r;
        const int p = pos[row];
#pragma unroll
        for (int jj = 0; jj < 2; ++jj) {
          const int d = (wn & 1) * 32 + jj * 16 + l15;  // 0..63
          const float c = cosT[p * HDIM + d];
          const float s = sinT[p * HDIM + d];
          const float lo = acc[i][jj][r], hi = acc[i][jj + 2][r];
          const int col = n0 + colbase + jj * 16 + l15;
          ((ushort*)Op)[(size_t)row * HID + col] = f2bf((lo * c - hi * s) * qsc);
          ((ushort*)Op)[(size_t)row * HID + col + 64] = f2bf((hi * c + lo * s) * qsc);
        }
      }
    }
  } else {
#pragma unroll
    for (int i = 0; i < 8; ++i) {
      const int row = m0 + wm * 128 + i * 16 + l4 * 4;
#pragma unroll
      for (int j = 0; j < 4; ++j) {
        const int col = n0 + colbase + (j & 1) * 16 + (j >> 1) * 64 + l15;
#pragma unroll
        for (int r = 0; r < 4; ++r) {
          float v = acc[i][j][r];
          if constexpr (OUTF32)
            ((float*)Op)[(size_t)(row + r) * HID + col] = v;
          else
            ((ushort*)Op)[(size_t)(row + r) * HID + col] = f2bf(v);
        }
      }
    }
  }
}

// ================= OLD 128x128 GEMM (fallback path only) =================
template <bool ISBF>
__device__ __forceinline__ void stage_tile(ushort* lds, const void* gp, int row0, int k0, int tid) {
  if constexpr (ISBF) {
    const ushort* g = (const ushort*)gp;
#pragma unroll
    for (int i = 0; i < 2; ++i) {
      int row = (tid >> 2) + i * 64;
      int gr = tid & 3;
      bf16x8 v = *(const bf16x8*)(g + (size_t)(row0 + row) * HID + k0 + gr * 8);
      int gs = gr ^ ((row >> 1) & 3);
      *(bf16x8*)((char*)lds + row * 64 + gs * 16) = v;
    }
  } else {
    const float* g = (const float*)gp;
    int row = tid >> 1;
    const float* rp = g + (size_t)(row0 + row) * HID + k0;
#pragma unroll
    for (int i = 0; i < 2; ++i) {
      int gr = (tid & 1) * 2 + i;
      float4 a = *(const float4*)(rp + gr * 8);
      float4 b = *(const float4*)(rp + gr * 8 + 4);
      bf16x8 v;
      v[0] = (short)f2bf(a.x); v[1] = (short)f2bf(a.y);
      v[2] = (short)f2bf(a.z); v[3] = (short)f2bf(a.w);
      v[4] = (short)f2bf(b.x); v[5] = (short)f2bf(b.y);
      v[6] = (short)f2bf(b.z); v[7] = (short)f2bf(b.w);
      int gs = gr ^ ((row >> 1) & 3);
      *(bf16x8*)((char*)lds + row * 64 + gs * 16) = v;
    }
  }
}

template <bool ABF, bool BBF, bool OUTF32>
__global__ __launch_bounds__(256) void gemm_bt_kernel(
    const void* __restrict__ Ap,
    const void* __restrict__ B0, const void* __restrict__ B1, const void* __restrict__ B2,
    void* __restrict__ O0, void* __restrict__ O1, void* __restrict__ O2,
    int ntiles_per_w) {
  __shared__ __align__(16) ushort lA[128 * 32];
  __shared__ __align__(16) ushort lB[128 * 32];
  const int tid = threadIdx.x;
  const int l = tid & 63, wid = tid >> 6;
  const int wm = wid >> 1, wn = wid & 1;
  const int l15 = l & 15, l4 = l >> 4;
  const int mt0 = blockIdx.y * 128;
  const int ntile = blockIdx.x;
  const int sel = ntile / ntiles_per_w;
  const int nt0 = (ntile % ntiles_per_w) * 128;
  const void* Bp = (sel == 0) ? B0 : ((sel == 1) ? B1 : B2);
  void* Op = (sel == 0) ? O0 : ((sel == 1) ? O1 : O2);

  const f32x4 zero = {0.f, 0.f, 0.f, 0.f};
  f32x4 acc[4][4];
#pragma unroll
  for (int i = 0; i < 4; ++i)
#pragma unroll
    for (int j = 0; j < 4; ++j) acc[i][j] = zero;

  for (int k0 = 0; k0 < HID; k0 += 32) {
    stage_tile<ABF>(lA, Ap, mt0, k0, tid);
    stage_tile<BBF>(lB, Bp, nt0, k0, tid);
    __syncthreads();
    bf16x8 af[4], bfr[4];
#pragma unroll
    for (int i = 0; i < 4; ++i) {
      int rowa = wm * 64 + i * 16 + l15;
      int ga = l4 ^ ((rowa >> 1) & 3);
      af[i] = *(const bf16x8*)((const char*)lA + rowa * 64 + ga * 16);
      int rowb = wn * 64 + i * 16 + l15;
      int gb = l4 ^ ((rowb >> 1) & 3);
      bfr[i] = *(const bf16x8*)((const char*)lB + rowb * 64 + gb * 16);
    }
#pragma unroll
    for (int i = 0; i < 4; ++i)
#pragma unroll
      for (int j = 0; j < 4; ++j)
        acc[i][j] = __builtin_amdgcn_mfma_f32_16x16x32_bf16(af[i], bfr[j], acc[i][j], 0, 0, 0);
    __syncthreads();
  }

#pragma unroll
  for (int i = 0; i < 4; ++i) {
#pragma unroll
    for (int j = 0; j < 4; ++j) {
      int row = mt0 + wm * 64 + i * 16 + l4 * 4;
      int col = nt0 + wn * 64 + j * 16 + l15;
#pragma unroll
      for (int r = 0; r < 4; ++r) {
        float v = acc[i][j][r];
        if constexpr (OUTF32)
          ((float*)Op)[(size_t)(row + r) * HID + col] = v;
        else
          ((ushort*)Op)[(size_t)(row + r) * HID + col] = f2bf(v);
      }
    }
  }
}

// ---------------- RoPE (fallback path only) ----------------
__global__ __launch_bounds__(256) void rope_kernel(
    ushort* __restrict__ q, ushort* __restrict__ k,
    const float* __restrict__ cosT, const float* __restrict__ sinT,
    const int* __restrict__ pos) {
  int idx = blockIdx.x * 256 + threadIdx.x;
  int token = idx >> 8;
  int head = (idx >> 3) & 31;
  int c = idx & 7;
  int p = pos[token];
  size_t base = (size_t)token * HID + head * HDIM + c * 8;
  bf16x8 ql = *(bf16x8*)(q + base);
  bf16x8 qh = *(bf16x8*)(q + base + 64);
  bf16x8 kl = *(bf16x8*)(k + base);
  bf16x8 kh = *(bf16x8*)(k + base + 64);
  float4 c0 = *(const float4*)(cosT + (size_t)p * HDIM + c * 8);
  float4 c1 = *(const float4*)(cosT + (size_t)p * HDIM + c * 8 + 4);
  float4 s0 = *(const float4*)(sinT + (size_t)p * HDIM + c * 8);
  float4 s1 = *(const float4*)(sinT + (size_t)p * HDIM + c * 8 + 4);
  float cs[8] = {c0.x, c0.y, c0.z, c0.w, c1.x, c1.y, c1.z, c1.w};
  float sn[8] = {s0.x, s0.y, s0.z, s0.w, s1.x, s1.y, s1.z, s1.w};
  const float qsc = 0.08838834764831845f;  // 1/sqrt(128)
  bf16x8 qlo, qho, klo, kho;
#pragma unroll
  for (int j = 0; j < 8; ++j) {
    float qlf = bf2f((ushort)ql[j]), qhf = bf2f((ushort)qh[j]);
    float klf = bf2f((ushort)kl[j]), khf = bf2f((ushort)kh[j]);
    qlo[j] = (short)f2bf((qlf * cs[j] - qhf * sn[j]) * qsc);
    qho[j] = (short)f2bf((qhf * cs[j] + qlf * sn[j]) * qsc);
    klo[j] = (short)f2bf(klf * cs[j] - khf * sn[j]);
    kho[j] = (short)f2bf(khf * cs[j] + klf * sn[j]);
  }
  *(bf16x8*)(q + base) = qlo;
  *(bf16x8*)(q + base + 64) = qho;
  *(bf16x8*)(k + base) = klo;
  *(bf16x8*)(k + base + 64) = kho;
}

// ---------------- causal flash attention (R19 exact -- best measured) ------
// grid (qblk=8, head=32, batch=8), 512 thr = 8 waves x 16 q-rows (QBLK=128).
// T14 async reg staging + LPT + frozen-max + deferred per-lane lrow.
__global__ __launch_bounds__(512) void attn_kernel(
    const ushort* __restrict__ qb, const ushort* __restrict__ kb,
    const ushort* __restrict__ vb, ushort* __restrict__ ob) {
  __shared__ __align__(16) ushort lK[32 * 128];   // [key][d], rows 256B, swz g^=(r&7)
  __shared__ __align__(16) ushort lVT[128 * 32];  // [d][key], rows 64B, swz g^=((d>>1)&3)
  __shared__ __align__(16) ushort lP[8][16 * 32]; // per-wave P [q][key]

  const int tid = threadIdx.x;
  const int l = tid & 63, wid = tid >> 6;
  const int l15 = l & 15, l4 = l >> 4;
  const int q0 = (gridDim.x - 1 - blockIdx.x) * 128;  // LPT: heavy first
  const int h = blockIdx.y;
  const size_t seqbase = (size_t)blockIdx.z * SEQ;

  const int sr = tid >> 4, sg = tid & 15;         // K: row sr, granule sg
  const int vd = tid & 127, vj0 = (tid >> 7) * 8; // V: col vd, keys vj0..vj0+7
  const ushort* kgp = kb + (seqbase + sr) * HID + h * HDIM + sg * 8;
  const ushort* vgp = vb + (seqbase + vj0) * HID + h * HDIM + vd;

  bf16x8 qf[4];
  {
    const ushort* qp = qb + (seqbase + q0 + wid * 16 + l15) * HID + h * HDIM + l4 * 8;
#pragma unroll
    for (int kk = 0; kk < 4; ++kk) qf[kk] = *(const bf16x8*)(qp + kk * 32);
  }

  const f32x4 zero = {0.f, 0.f, 0.f, 0.f};
  f32x4 oacc[8];
#pragma unroll
  for (int t = 0; t < 8; ++t) oacc[t] = zero;
  float mrow[4];
  float lrow[4] = {0.f, 0.f, 0.f, 0.f};  // per-lane partial sums

  const int ntile = q0 / 32 + 4;
  const int qrow = q0 + wid * 16 + l4 * 4;

  bf16x8 kreg = *(const bf16x8*)(kgp);
  bf16x8 vreg;
#pragma unroll
  for (int j = 0; j < 8; ++j) vreg[j] = (short)vgp[(size_t)j * HID];

  for (int kt = 0; kt < ntile; ++kt) {
    const int k0 = kt * 32;
    __builtin_amdgcn_s_barrier();
    {
      int gs = sg ^ (sr & 7);
      *(bf16x8*)((char*)lK + sr * 256 + gs * 16) = kreg;
    }
    {
      int g = tid >> 7;
      int gs = g ^ ((vd >> 1) & 3);
      *(bf16x8*)((char*)lVT + vd * 64 + gs * 16) = vreg;
    }
    if (kt + 1 < ntile) {
      const size_t off = (size_t)(k0 + 32) * HID;
      kreg = *(const bf16x8*)(kgp + off);
#pragma unroll
      for (int j = 0; j < 8; ++j) vreg[j] = (short)vgp[off + (size_t)j * HID];
    }
    __syncthreads();

    f32x4 s[2];
#pragma unroll
    for (int hf = 0; hf < 2; ++hf) {
      f32x4 c = zero;
      int row = hf * 16 + l15;
#pragma unroll
      for (int kk = 0; kk < 4; ++kk) {
        int gs = (kk * 4 + l4) ^ (row & 7);
        bf16x8 kf = *(const bf16x8*)((const char*)lK + row * 256 + gs * 16);
        c = __builtin_amdgcn_mfma_f32_16x16x32_bf16(qf[kk], kf, c, 0, 0, 0);
      }
      s[hf] = c;
    }

    if (kt == 0) {
#pragma unroll
      for (int r = 0; r < 4; ++r) {
        float s0 = (k0 + l15 <= qrow + r) ? s[0][r] : -1e30f;
        float s1 = (k0 + 16 + l15 <= qrow + r) ? s[1][r] : -1e30f;
        float tmax = fmaxf(s0, s1);
#pragma unroll
        for (int off = 8; off; off >>= 1) tmax = fmaxf(tmax, __shfl_xor(tmax, off));
        mrow[r] = tmax;
        float p0 = __expf(s0 - tmax);
        float p1 = __expf(s1 - tmax);
        lrow[r] = p0 + p1;  // per-lane partial
        lP[wid][(l4 * 4 + r) * 32 + l15] = f2bf(p0);
        lP[wid][(l4 * 4 + r) * 32 + 16 + l15] = f2bf(p1);
      }
    } else {
#pragma unroll
      for (int r = 0; r < 4; ++r) {
        float s0 = (k0 + l15 <= qrow + r) ? s[0][r] : -1e30f;
        float s1 = (k0 + 16 + l15 <= qrow + r) ? s[1][r] : -1e30f;
        float p0 = __expf(s0 - mrow[r]);
        float p1 = __expf(s1 - mrow[r]);
        lrow[r] += p0 + p1;
        lP[wid][(l4 * 4 + r) * 32 + l15] = f2bf(p0);
        lP[wid][(l4 * 4 + r) * 32 + 16 + l15] = f2bf(p1);
      }
    }
    asm volatile("s_waitcnt lgkmcnt(0)" ::: "memory");
    __builtin_amdgcn_sched_barrier(0);

    bf16x8 pf = *(const bf16x8*)((const char*)&lP[wid][0] + l15 * 64 + l4 * 16);
#pragma unroll
    for (int t = 0; t < 8; ++t) {
      int d = t * 16 + l15;
      int gs = l4 ^ ((d >> 1) & 3);
      bf16x8 vf = *(const bf16x8*)((const char*)lVT + d * 64 + gs * 16);
      oacc[t] = __builtin_amdgcn_mfma_f32_16x16x32_bf16(pf, vf, oacc[t], 0, 0, 0);
    }
  }

  // epilogue: single 16-lane reduction of the deferred denominator
#pragma unroll
  for (int r = 0; r < 4; ++r) {
#pragma unroll
    for (int off = 8; off; off >>= 1) lrow[r] += __shfl_xor(lrow[r], off);
    float inv = 1.0f / lrow[r];
    ushort* op = ob + (seqbase + q0 + wid * 16 + l4 * 4 + r) * HID + h * HDIM + l15;
#pragma unroll
    for (int t = 0; t < 8; ++t) op[t * 16] = f2bf(oacc[t][r] * inv);
  }
}

// ---------------- driver ----------------
extern "C" void kernel_launch(void* const* d_in, const int* in_sizes, int n_in,
                              void* d_out, int out_size, void* d_ws, size_t ws_size,
                              hipStream_t stream) {
  const float* cosT = (const float*)d_in[0];
  const float* sinT = (const float*)d_in[1];
  const float* X    = (const float*)d_in[2];
  const int*   pos  = (const int*)d_in[3];
  const float* Wq = (const float*)d_in[6];
  const float* Wk = (const float*)d_in[7];
  const float* Wv = (const float*)d_in[8];
  const float* Wo = (const float*)d_in[9];
  float* out = (float*)d_out;

  char* ws = (char*)d_ws;
  const size_t QKVB = (size_t)NTOK * HID * 2;  // 64 MiB
  const size_t WB = (size_t)HID * HID * 2;     // 32 MiB
  const size_t XB = QKVB;
  ushort* qbuf = (ushort*)(ws);
  ushort* kbuf = (ushort*)(ws + QKVB);
  ushort* vbuf = (ushort*)(ws + 2 * QKVB);

  dim3 blk(256);
  const int n4x = NTOK * HID / 4;
  const int n4w = HID * HID / 4;

  const bool fast = ws_size >= 3 * QKVB + XB + 4 * WB;          // 384 MiB
  const bool mid = !fast && ws_size >= 3 * QKVB + 2 * WB &&
                   (size_t)out_size * 4 >= XB + 2 * WB;          // 256 MiB + d_out scratch

  if (fast || mid) {
    ushort *xb, *wqb, *wkb, *wvb, *wob;
    if (fast) {
      xb  = (ushort*)(ws + 3 * QKVB);
      wqb = (ushort*)(ws + 3 * QKVB + XB);
      wkb = (ushort*)(ws + 3 * QKVB + XB + WB);
      wvb = (ushort*)(ws + 3 * QKVB + XB + 2 * WB);
      wob = (ushort*)(ws + 3 * QKVB + XB + 3 * WB);
    } else {
      // stash X/Wq/Wk bf16 in d_out (fully overwritten by final GEMM)
      xb  = (ushort*)d_out;
      wqb = (ushort*)((char*)d_out + XB);
      wkb = (ushort*)((char*)d_out + XB + WB);
      wvb = (ushort*)(ws + 3 * QKVB);
      wob = (ushort*)(ws + 3 * QKVB + WB);
    }
    cvt_bf16_kernel<<<n4x / 256, blk, 0, stream>>>((const float4*)X, (ushort4*)xb, n4x);
    cvt4_bf16_kernel<<<dim3(n4w / 256, 4), blk, 0, stream>>>(
        (const float4*)Wq, (const float4*)Wk, (const float4*)Wv, (const float4*)Wo,
        (ushort4*)wqb, (ushort4*)wkb, (ushort4*)wvb, (ushort4*)wob, n4w);
    gemm256_kernel<false, true><<<dim3(32 * 48), dim3(512), 0, stream>>>(
        xb, wqb, wkb, wvb, qbuf, kbuf, vbuf, 48, pos, cosT, sinT);
    attn_kernel<<<dim3(8, 32, 8), dim3(512), 0, stream>>>(qbuf, kbuf, vbuf, qbuf);
    gemm256_kernel<true, false><<<dim3(32 * 16), dim3(512), 0, stream>>>(
        qbuf, wob, wob, wob, out, out, out, 16, pos, cosT, sinT);
  } else {
    gemm_bt_kernel<false, false, false><<<dim3(96, 64), blk, 0, stream>>>(
        X, Wq, Wk, Wv, qbuf, kbuf, vbuf, 32);
    rope_kernel<<<NTOK * NHEADS * 8 / 256, blk, 0, stream>>>(qbuf, kbuf, cosT, sinT, pos);
    attn_kernel<<<dim3(8, 32, 8), dim3(512), 0, stream>>>(qbuf, kbuf, vbuf, qbuf);
    gemm_bt_kernel<true, false, true><<<dim3(32, 64), blk, 0, stream>>>(
        qbuf, Wo, Wo, Wo, out, out, out, 32);
  }
}